// Round 13
// baseline (762.267 us; speedup 1.0000x reference)
//
#include <hip/hip_runtime.h>
#include <hip/hip_bf16.h>
#include <stdint.h>

#define NNODE 65536
#define NEDGE 65536
#define ETOT  (NNODE + NEDGE)
#define INC   512
#define OUTC  256
#define NEG_SLOPE 0.2f
#define SLOTCAP 32

typedef __attribute__((ext_vector_type(8))) __bf16 bf16x8;
typedef __attribute__((ext_vector_type(4))) float f32x4;

__device__ __forceinline__ float b2f(unsigned short u) {
  return __uint_as_float(((unsigned int)u) << 16);
}
__device__ __forceinline__ unsigned short f2b(float f) {
  unsigned int u = __float_as_uint(f);
  u += 0x7fffu + ((u >> 16) & 1u);
  return (unsigned short)(u >> 16);
}
__device__ __forceinline__ unsigned int pk2(float lo, float hi) {
  return (unsigned int)f2b(lo) | ((unsigned int)f2b(hi) << 16);
}
__device__ __forceinline__ float lrelu(float v) {
  return v > 0.f ? v : NEG_SLOPE * v;
}

// ---------------- prep (merged): x->bf16, W concat transpose, bias concat, cnt zero ------------
__global__ __launch_bounds__(256) void prep_kernel(
    const float* __restrict__ x, unsigned short* __restrict__ xb, int* __restrict__ cnt,
    const float* __restrict__ Wl, const float* __restrict__ Wr, const float* __restrict__ Ws,
    const float* __restrict__ bl, const float* __restrict__ br, const float* __restrict__ bs,
    unsigned short* __restrict__ WT, float* __restrict__ bcat) {
  const int b = blockIdx.x, t = threadIdx.x;
  // x cvt: all 16384 blocks, 8 f32 each
  size_t i = ((size_t)b * 256 + t) * 8;
  float4 v0 = *(const float4*)(x + i);
  float4 v1 = *(const float4*)(x + i + 4);
  uint4 o;
  o.x = pk2(v0.x, v0.y);
  o.y = pk2(v0.z, v0.w);
  o.z = pk2(v1.x, v1.y);
  o.w = pk2(v1.z, v1.w);
  *(uint4*)(xb + i) = o;
  if (b < 256) cnt[b * 256 + t] = 0;
  const int wi = b * 256 + t;
  if (wi < 768 * 512) {
    const int oc = wi >> 9, k = wi & 511;
    float v;
    if (oc < 256)      v = Wl[k * 256 + oc];
    else if (oc < 512) v = Wr[k * 256 + (oc - 256)];
    else               v = Ws[k * 256 + (oc - 512)];
    WT[wi] = f2b(v);
  }
  if (wi < 768) {
    bcat[wi] = (wi < 256) ? bl[wi] : (wi < 512 ? br[wi - 256] : bs[wi - 512]);
  }
}

// ---------------- fused GEMM: 2-buffer 64KB ring -> 2 blocks/CU (occupancy fills bubbles) ------
// 256x256 tile, BK=32, 16 K-tiles. T3-min schedule: per iter {stage(t+1) into freed buf |
// 12 ds_read frags(t) | lgkmcnt(0) | 32-MFMA setprio cluster | vmcnt(0) | barrier}. The drain is
// issued ~450cyc after the stage, and the co-resident second block (m114) fills the residue.
// T1 XCD swizzle, T2 XOR slot swizzle via pre-swizzled source (rule 21), T5 setprio.
// GEMV epilogue: by=0 -> g=dot(xl,Wcls), by=2 -> gs=dot(xs,Wcls) (block-local reduce).
__global__ __launch_bounds__(512, 4) void gemm_kernel(
    const unsigned short* __restrict__ Xb,   // [65536][512]
    const unsigned short* __restrict__ WT,   // [768][512]
    const float* __restrict__ bcat,          // [768]
    const float* __restrict__ Wcls,          // [256]
    unsigned short* __restrict__ xl,
    unsigned short* __restrict__ xr,
    unsigned short* __restrict__ xs,
    float* __restrict__ g,                   // [65536] dot(xl,Wcls)
    float* __restrict__ gs) {                // [65536] dot(xs,Wcls)
  __shared__ __align__(16) char smem[65536];      // ring: 2 bufs x (A 16KB + B 16KB)
  unsigned short* ring = (unsigned short*)smem;   // buf b at b*16384 shorts; B at +8192

  const int wid = blockIdx.x;
  const int xcd = wid & 7;
  const int local = wid >> 3;              // 0..95
  const int by = local % 3;                // col tile 0..2  (0->xl, 1->xr, 2->xs)
  const int rowt = xcd * 32 + local / 3;   // row tile 0..255
  const int rowBase = rowt * 256;
  const int colBase = by * 256;

  const int tid = threadIdx.x;
  const int lane = tid & 63;
  const int w = tid >> 6;        // wave 0..7
  const int wm = (w >> 2) * 128; // wave row offset
  const int wn = (w & 3) * 64;   // wave col offset

  f32x4 acc[8][4] = {};

  auto stageh = [&](int c, int hf) {
    const int kk = c * 32;
    const int buf = c & 1;
    const int q = tid;
    const int sl = q & 3;
    const unsigned short* basep = hf ? (WT + (size_t)colBase * 512) : (Xb + (size_t)rowBase * 512);
    unsigned short* ldst = ring + buf * 16384 + hf * 8192;
#pragma unroll
    for (int l = 0; l < 2; ++l) {
      const int r = l * 128 + (q >> 2);            // tile row 0..255
      const int slot = sl ^ ((r >> 1) & 3);        // involution (rule 21)
      const unsigned short* gp = basep + (size_t)r * 512 + kk + slot * 8;
      __builtin_amdgcn_global_load_lds(
          (const __attribute__((address_space(1))) void*)gp,
          (__attribute__((address_space(3))) void*)(ldst + l * 4096 + q * 8), 16, 0, 0);
    }
  };

  // prologue: tile 0 staged and landed
  stageh(0, 0); stageh(0, 1);
  asm volatile("s_waitcnt vmcnt(0)" ::: "memory");
  __builtin_amdgcn_s_barrier();
  __builtin_amdgcn_sched_barrier(0);

#pragma unroll
  for (int c = 0; c < 16; ++c) {
    const unsigned short* As = ring + (c & 1) * 16384;
    const unsigned short* Bs = As + 8192;
    const int kq = lane >> 4;
    bf16x8 fa[8], fb[4];

    // stage next tile into the buffer freed at the previous barrier
    if (c + 1 < 16) { stageh(c + 1, 0); stageh(c + 1, 1); }

    // read this tile's fragments (12 x ds_read_b128)
#pragma unroll
    for (int m = 0; m < 8; ++m) {
      const int rA = wm + m * 16 + (lane & 15);
      fa[m] = *(const bf16x8*)&As[rA * 32 + ((kq ^ ((rA >> 1) & 3)) << 3)];
    }
#pragma unroll
    for (int n = 0; n < 4; ++n) {
      const int rB = wn + n * 16 + (lane & 15);
      fb[n] = *(const bf16x8*)&Bs[rB * 32 + ((kq ^ ((rB >> 1) & 3)) << 3)];
    }
    asm volatile("s_waitcnt lgkmcnt(0)" ::: "memory");
    __builtin_amdgcn_sched_barrier(0);
    __builtin_amdgcn_s_setprio(1);
#pragma unroll
    for (int m = 0; m < 8; ++m)
#pragma unroll
      for (int n = 0; n < 4; ++n)
        acc[m][n] = __builtin_amdgcn_mfma_f32_16x16x32_bf16(fa[m], fb[n], acc[m][n], 0, 0, 0);
    __builtin_amdgcn_s_setprio(0);
    // next tile landed (issued ~450cyc ago, mostly hidden); then everyone past reads of this buf
    asm volatile("s_waitcnt vmcnt(0)" ::: "memory");
    __builtin_amdgcn_s_barrier();
    __builtin_amdgcn_sched_barrier(0);
  }

  // epilogue: bf16 stores via per-wave-private LDS restage + fused row-dot (g/gs).
  // D frag layout: col = lane&15, row = (lane>>4)*4 + j   [m89-verified]
  {
    unsigned short* dst = (by == 0) ? xl : (by == 1) ? xr : xs;
    const bool doG = (by != 1);
    float* eps = (float*)smem + w * 1088;          // 16x68 f32 private (<= 34816B)
    float* gpart = (float*)(smem + 40960);         // [256][4] f32 = 4KB
    float biasn[4], wcn[4];
#pragma unroll
    for (int n = 0; n < 4; ++n) {
      biasn[n] = bcat[colBase + wn + n * 16 + (lane & 15)];
      wcn[n] = Wcls[wn + n * 16 + (lane & 15)];
    }
#pragma unroll
    for (int m = 0; m < 8; ++m) {
      float rp[4] = {0.f, 0.f, 0.f, 0.f};
#pragma unroll
      for (int n = 0; n < 4; ++n)
#pragma unroll
        for (int j = 0; j < 4; ++j) {
          const float v = acc[m][n][j] + biasn[n];
          eps[((lane >> 4) * 4 + j) * 68 + n * 16 + (lane & 15)] = v;
          rp[j] += v * wcn[n];
        }
#pragma unroll
      for (int it = 0; it < 2; ++it) {
        const int r16 = it * 8 + (lane >> 3);
        const int c8 = (lane & 7) * 8;
        const float* srcp = eps + r16 * 68 + c8;
        float4 v0 = *(const float4*)srcp;
        float4 v1 = *(const float4*)(srcp + 4);
        uint4 o;
        o.x = pk2(v0.x, v0.y);
        o.y = pk2(v0.z, v0.w);
        o.z = pk2(v1.x, v1.y);
        o.w = pk2(v1.z, v1.w);
        *(uint4*)(dst + (size_t)(rowBase + wm + m * 16 + r16) * 256 + wn + c8) = o;
      }
      if (doG) {
#pragma unroll
        for (int j = 0; j < 4; ++j) {
          float s = rp[j];
          s += __shfl_xor(s, 1);
          s += __shfl_xor(s, 2);
          s += __shfl_xor(s, 4);
          s += __shfl_xor(s, 8);
          if ((lane & 15) == 0)
            gpart[(wm + m * 16 + (lane >> 4) * 4 + j) * 4 + (w & 3)] = s;
        }
      }
    }
    __syncthreads();
    if (doG && tid < 256) {
      float s = gpart[tid * 4] + gpart[tid * 4 + 1] + gpart[tid * 4 + 2] + gpart[tid * 4 + 3];
      ((by == 0) ? g : gs)[rowBase + tid] = s;
    }
  }
}

// ---------------- per-edge attention logits (half-wave per edge) + direct slot scatter ----------------
__global__ __launch_bounds__(256) void edge_logit_kernel(
    const int* __restrict__ ei,          // [2][NEDGE]
    const unsigned short* __restrict__ xl,
    const unsigned short* __restrict__ xr,
    const float* __restrict__ att,
    int* __restrict__ cnt,
    int* __restrict__ slot_src,          // [NNODE][SLOTCAP]
    float* __restrict__ slot_e) {        // [NNODE][SLOTCAP]
  const int j = blockIdx.x * 8 + (threadIdx.x >> 5);
  const int lane = threadIdx.x & 31;
  int src, dst;
  if (j < NEDGE) { src = ei[j]; dst = ei[NEDGE + j]; }
  else           { src = j - NEDGE; dst = src; }
  const int c = lane * 8;
  uint4 ul = *(const uint4*)(xl + (size_t)src * 256 + c);
  uint4 ur = *(const uint4*)(xr + (size_t)dst * 256 + c);
  float4 a0 = *(const float4*)(att + c);
  float4 a1 = *(const float4*)(att + c + 4);
  float s = lrelu(b2f((unsigned short)ul.x) + b2f((unsigned short)ur.x)) * a0.x
          + lrelu(b2f((unsigned short)(ul.x >> 16)) + b2f((unsigned short)(ur.x >> 16))) * a0.y
          + lrelu(b2f((unsigned short)ul.y) + b2f((unsigned short)ur.y)) * a0.z
          + lrelu(b2f((unsigned short)(ul.y >> 16)) + b2f((unsigned short)(ur.y >> 16))) * a0.w
          + lrelu(b2f((unsigned short)ul.z) + b2f((unsigned short)ur.z)) * a1.x
          + lrelu(b2f((unsigned short)(ul.z >> 16)) + b2f((unsigned short)(ur.z >> 16))) * a1.y
          + lrelu(b2f((unsigned short)ul.w) + b2f((unsigned short)ur.w)) * a1.z
          + lrelu(b2f((unsigned short)(ul.w >> 16)) + b2f((unsigned short)(ur.w >> 16))) * a1.w;
#pragma unroll
  for (int off = 16; off; off >>= 1) s += __shfl_xor(s, off);
  if (lane == 0) {
    const int pos = atomicAdd(&cnt[dst], 1);
    if (pos < SLOTCAP) {
      slot_src[dst * SLOTCAP + pos] = src;
      slot_e[dst * SLOTCAP + pos] = s;
    }
  }
}

// ---------------- per-node cls logit from g/gs (softmax shift-invariance drops the const) ------
__global__ __launch_bounds__(256) void logit_kernel(
    const int* __restrict__ cnt,
    const int* __restrict__ slot_src, const float* __restrict__ slot_e,
    const float* __restrict__ g, const float* __restrict__ gs,
    float* __restrict__ logits) {
  const int n = blockIdx.x * 256 + threadIdx.x;
  const int base = n * SLOTCAP;
  const int deg = cnt[n];
  float m = -1e30f;
  for (int k = 0; k < deg; ++k) m = fmaxf(m, slot_e[base + k]);
  float denom = 0.f, wsum = 0.f;
  for (int k = 0; k < deg; ++k) {
    const float p = __expf(slot_e[base + k] - m);
    denom += p;
    wsum += p * g[slot_src[base + k]];
  }
  logits[n] = gs[n] + wsum / denom;
}

// ---------------- per-node softmax + aggregate + fused sinkhorn add (wave per node) ----------------
__global__ __launch_bounds__(256) void node_sk_kernel(
    const int* __restrict__ cnt,
    const int* __restrict__ slot_src, const float* __restrict__ slot_e,
    const unsigned short* __restrict__ xl,
    const unsigned short* __restrict__ xs,
    const float* __restrict__ conv_bias,
    const float* __restrict__ logits,
    float* __restrict__ out) {
  const int n = blockIdx.x * 4 + (threadIdx.x >> 6);
  const int lane = threadIdx.x & 63;
  const int base = n * SLOTCAP;
  const int deg = cnt[n];

  float m = -1e30f;
  for (int k = 0; k < deg; ++k) m = fmaxf(m, slot_e[base + k]);
  float denom = 0.f;
  for (int k = 0; k < deg; ++k) denom += __expf(slot_e[base + k] - m);
  const float inv = 1.f / denom;

  const int c = lane * 4;
  float4 accv = {0.f, 0.f, 0.f, 0.f};
  for (int k = 0; k < deg; ++k) {
    const float alpha = __expf(slot_e[base + k] - m) * inv;
    const int src = slot_src[base + k];
    ushort4 u = *(const ushort4*)(xl + (size_t)src * 256 + c);
    accv.x += alpha * b2f(u.x);
    accv.y += alpha * b2f(u.y);
    accv.z += alpha * b2f(u.z);
    accv.w += alpha * b2f(u.w);
  }

  // row softmax of logits (sinkhorn channel): wave holds all 256 row logits (4/lane)
  const int r = n >> 8;
  float4 lv = *(const float4*)(logits + r * 256 + c);
  float lm = fmaxf(fmaxf(lv.x, lv.y), fmaxf(lv.z, lv.w));
#pragma unroll
  for (int off = 32; off; off >>= 1) lm = fmaxf(lm, __shfl_xor(lm, off));
  float ls = __expf(lv.x - lm) + __expf(lv.y - lm) + __expf(lv.z - lm) + __expf(lv.w - lm);
#pragma unroll
  for (int off = 32; off; off >>= 1) ls += __shfl_xor(ls, off);
  const float softval = __expf(logits[n] - lm) / ls;

  ushort4 s4 = *(const ushort4*)(xs + (size_t)n * 256 + c);
  float4 cb = *(const float4*)(conv_bias + c);
  float4 cur;
  cur.x = b2f(s4.x) + accv.x + cb.x + softval;
  cur.y = b2f(s4.y) + accv.y + cb.y + softval;
  cur.z = b2f(s4.z) + accv.z + cb.z + softval;
  cur.w = b2f(s4.w) + accv.w + cb.w + softval;
  *(float4*)(out + (size_t)n * 256 + c) = cur;
}

// ---------------- launch ----------------
extern "C" void kernel_launch(void* const* d_in, const int* in_sizes, int n_in,
                              void* d_out, int out_size, void* d_ws, size_t ws_size,
                              hipStream_t stream) {
  const float* x        = (const float*)d_in[0];
  const int*   ei       = (const int*)d_in[2];
  const float* W_self   = (const float*)d_in[5];
  const float* b_self   = (const float*)d_in[6];
  const float* W_l      = (const float*)d_in[7];
  const float* b_l      = (const float*)d_in[8];
  const float* W_r      = (const float*)d_in[9];
  const float* b_r      = (const float*)d_in[10];
  const float* att      = (const float*)d_in[11];
  const float* conv_bias= (const float*)d_in[12];
  const float* W_cls    = (const float*)d_in[13];
  float* out = (float*)d_out;

  char* ws = (char*)d_ws;
  size_t off = 0;
  auto alloc = [&](size_t bytes) {
    char* p = ws + off;
    off += (bytes + 255) & ~(size_t)255;
    return p;
  };
  unsigned short* xb   = (unsigned short*)alloc((size_t)NNODE * INC * 2);  // dead after gemm
  unsigned short* WT   = (unsigned short*)alloc((size_t)768 * 512 * 2);
  float*          bcat = (float*)alloc(768 * 4);
  unsigned short* xlb  = (unsigned short*)alloc((size_t)NNODE * OUTC * 2);
  unsigned short* xrb  = (unsigned short*)alloc((size_t)NNODE * OUTC * 2);
  unsigned short* xsb  = (unsigned short*)alloc((size_t)NNODE * OUTC * 2);
  int*            cnt  = (int*)alloc((size_t)NNODE * 4);
  float*          logits  = (float*)alloc((size_t)NNODE * 4);
  float*          gbuf    = (float*)alloc((size_t)NNODE * 4);
  float*          gsbuf   = (float*)alloc((size_t)NNODE * 4);
  // slot arrays overlay xb (dead after gemm)
  int*   slot_src = (int*)xb;
  float* slot_e   = (float*)(xb + (size_t)NNODE * SLOTCAP * 2);
  (void)ws_size; (void)in_sizes; (void)n_in; (void)out_size;

  prep_kernel<<<(NNODE * INC) / (256 * 8), 256, 0, stream>>>(x, xb, cnt,
                                                             W_l, W_r, W_self, b_l, b_r, b_self,
                                                             WT, bcat);
  gemm_kernel<<<768, 512, 0, stream>>>(xb, WT, bcat, W_cls, xlb, xrb, xsb, gbuf, gsbuf);
  edge_logit_kernel<<<ETOT / 8, 256, 0, stream>>>(ei, xlb, xrb, att, cnt, slot_src, slot_e);
  logit_kernel<<<NNODE / 256, 256, 0, stream>>>(cnt, slot_src, slot_e, gbuf, gsbuf, logits);
  node_sk_kernel<<<NNODE / 4, 256, 0, stream>>>(cnt, slot_src, slot_e, xlb, xsb, conv_bias,
                                                logits, out);
}

// Round 14
// 188.763 us; speedup vs baseline: 4.0382x; 4.0382x over previous
//
#include <hip/hip_runtime.h>
#include <hip/hip_bf16.h>
#include <stdint.h>

#define NNODE 65536
#define NEDGE 65536
#define ETOT  (NNODE + NEDGE)
#define INC   512
#define OUTC  256
#define NEG_SLOPE 0.2f
#define SLOTCAP 32

typedef __attribute__((ext_vector_type(8))) __bf16 bf16x8;
typedef __attribute__((ext_vector_type(4))) float f32x4;

__device__ __forceinline__ float b2f(unsigned short u) {
  return __uint_as_float(((unsigned int)u) << 16);
}
__device__ __forceinline__ unsigned short f2b(float f) {
  unsigned int u = __float_as_uint(f);
  u += 0x7fffu + ((u >> 16) & 1u);
  return (unsigned short)(u >> 16);
}
__device__ __forceinline__ unsigned int pk2(float lo, float hi) {
  return (unsigned int)f2b(lo) | ((unsigned int)f2b(hi) << 16);
}
__device__ __forceinline__ float lrelu(float v) {
  return v > 0.f ? v : NEG_SLOPE * v;
}

// ---------------- prep (merged): x->bf16, W concat transpose, bias concat, cnt zero ------------
__global__ __launch_bounds__(256) void prep_kernel(
    const float* __restrict__ x, unsigned short* __restrict__ xb, int* __restrict__ cnt,
    const float* __restrict__ Wl, const float* __restrict__ Wr, const float* __restrict__ Ws,
    const float* __restrict__ bl, const float* __restrict__ br, const float* __restrict__ bs,
    unsigned short* __restrict__ WT, float* __restrict__ bcat) {
  const int b = blockIdx.x, t = threadIdx.x;
  size_t i = ((size_t)b * 256 + t) * 8;
  float4 v0 = *(const float4*)(x + i);
  float4 v1 = *(const float4*)(x + i + 4);
  uint4 o;
  o.x = pk2(v0.x, v0.y);
  o.y = pk2(v0.z, v0.w);
  o.z = pk2(v1.x, v1.y);
  o.w = pk2(v1.z, v1.w);
  *(uint4*)(xb + i) = o;
  if (b < 256) cnt[b * 256 + t] = 0;
  const int wi = b * 256 + t;
  if (wi < 768 * 512) {
    const int oc = wi >> 9, k = wi & 511;
    float v;
    if (oc < 256)      v = Wl[k * 256 + oc];
    else if (oc < 512) v = Wr[k * 256 + (oc - 256)];
    else               v = Ws[k * 256 + (oc - 512)];
    WT[wi] = f2b(v);
  }
  if (wi < 768) {
    bcat[wi] = (wi < 256) ? bl[wi] : (wi < 512 ? br[wi - 256] : bs[wi - 512]);
  }
}

// ---------------- fused GEMM (R12-verified 8-phase core) + fused GEMV epilogue -----------------
// 256x256 tile, BK=32, 16 K-tiles; 3-buffer ring (32KB each). 2 phases/K-tile, each = {ds_read
// frags | stage half-tile | barrier | lgkmcnt(0) | 16-MFMA setprio cluster | barrier}; counted
// vmcnt(4) once per K-tile (drain only at c=14). T1 XCD swizzle, T2 XOR slot swizzle via
// pre-swizzled source (rule 21), T5 setprio. NOTE: no min-waves launch-bound — acc[8][4] needs
// ~200 unified regs/wave; capping at 128 spills accumulators to scratch (R13: 10x regression).
__global__ __launch_bounds__(512) void gemm_kernel(
    const unsigned short* __restrict__ Xb,   // [65536][512]
    const unsigned short* __restrict__ WT,   // [768][512]
    const float* __restrict__ bcat,          // [768]
    const float* __restrict__ Wcls,          // [256]
    unsigned short* __restrict__ xl,
    unsigned short* __restrict__ xr,
    unsigned short* __restrict__ xs,
    float* __restrict__ g,                   // [65536] dot(xl,Wcls)
    float* __restrict__ gs) {                // [65536] dot(xs,Wcls)
  __shared__ __align__(16) char smem[98304];      // ring: 3 bufs x (A 16KB + B 16KB)
  unsigned short* ring = (unsigned short*)smem;   // buf b at b*16384 shorts; B at +8192

  const int wid = blockIdx.x;
  const int xcd = wid & 7;
  const int local = wid >> 3;              // 0..95
  const int by = local % 3;                // col tile 0..2  (0->xl, 1->xr, 2->xs)
  const int rowt = xcd * 32 + local / 3;   // row tile 0..255
  const int rowBase = rowt * 256;
  const int colBase = by * 256;

  const int tid = threadIdx.x;
  const int lane = tid & 63;
  const int w = tid >> 6;        // wave 0..7
  const int wm = (w >> 2) * 128; // wave row offset
  const int wn = (w & 3) * 64;   // wave col offset

  f32x4 acc[8][4] = {};

  auto stageh = [&](int c, int hf) {
    const int kk = c * 32;
    const int buf = c % 3;
    const int q = tid;
    const int sl = q & 3;
    const unsigned short* basep = hf ? (WT + (size_t)colBase * 512) : (Xb + (size_t)rowBase * 512);
    unsigned short* ldst = ring + buf * 16384 + hf * 8192;
#pragma unroll
    for (int l = 0; l < 2; ++l) {
      const int r = l * 128 + (q >> 2);            // tile row 0..255
      const int slot = sl ^ ((r >> 1) & 3);        // involution (rule 21)
      const unsigned short* gp = basep + (size_t)r * 512 + kk + slot * 8;
      __builtin_amdgcn_global_load_lds(
          (const __attribute__((address_space(1))) void*)gp,
          (__attribute__((address_space(3))) void*)(ldst + l * 4096 + q * 8), 16, 0, 0);
    }
  };

  // prologue: tiles 0 and 1 staged; tile 0 landed
  stageh(0, 0); stageh(0, 1);
  stageh(1, 0); stageh(1, 1);
  asm volatile("s_waitcnt vmcnt(4)" ::: "memory");
  __builtin_amdgcn_s_barrier();

#pragma unroll
  for (int c = 0; c < 16; ++c) {
    const unsigned short* As = ring + (c % 3) * 16384;
    const unsigned short* Bs = As + 8192;
    const int kq = lane >> 4;
    bf16x8 fa[8], fb[4];

    // ---- even phase: read A m0-3 + B n0-3; stage A-half of tile c+2 ----
#pragma unroll
    for (int m = 0; m < 4; ++m) {
      const int rA = wm + m * 16 + (lane & 15);
      fa[m] = *(const bf16x8*)&As[rA * 32 + ((kq ^ ((rA >> 1) & 3)) << 3)];
    }
#pragma unroll
    for (int n = 0; n < 4; ++n) {
      const int rB = wn + n * 16 + (lane & 15);
      fb[n] = *(const bf16x8*)&Bs[rB * 32 + ((kq ^ ((rB >> 1) & 3)) << 3)];
    }
    if (c + 2 < 16) stageh(c + 2, 0);
    __builtin_amdgcn_s_barrier();
    asm volatile("s_waitcnt lgkmcnt(0)" ::: "memory");
    __builtin_amdgcn_sched_barrier(0);
    __builtin_amdgcn_s_setprio(1);
#pragma unroll
    for (int m = 0; m < 4; ++m)
#pragma unroll
      for (int n = 0; n < 4; ++n)
        acc[m][n] = __builtin_amdgcn_mfma_f32_16x16x32_bf16(fa[m], fb[n], acc[m][n], 0, 0, 0);
    __builtin_amdgcn_s_setprio(0);
    __builtin_amdgcn_s_barrier();

    // ---- odd phase: read A m4-7; stage B-half of tile c+2 ----
#pragma unroll
    for (int m = 4; m < 8; ++m) {
      const int rA = wm + m * 16 + (lane & 15);
      fa[m] = *(const bf16x8*)&As[rA * 32 + ((kq ^ ((rA >> 1) & 3)) << 3)];
    }
    if (c + 2 < 16) stageh(c + 2, 1);
    __builtin_amdgcn_s_barrier();
    asm volatile("s_waitcnt lgkmcnt(0)" ::: "memory");
    __builtin_amdgcn_sched_barrier(0);
    __builtin_amdgcn_s_setprio(1);
#pragma unroll
    for (int m = 4; m < 8; ++m)
#pragma unroll
      for (int n = 0; n < 4; ++n)
        acc[m][n] = __builtin_amdgcn_mfma_f32_16x16x32_bf16(fa[m], fb[n], acc[m][n], 0, 0, 0);
    __builtin_amdgcn_s_setprio(0);
    if (c <= 13)      asm volatile("s_waitcnt vmcnt(4)" ::: "memory");
    else if (c == 14) asm volatile("s_waitcnt vmcnt(0)" ::: "memory");
    __builtin_amdgcn_s_barrier();
  }

  // epilogue: bf16 stores via per-wave-private LDS restage + fused row-dot (g/gs).
  // D frag layout: col = lane&15, row = (lane>>4)*4 + j   [m89-verified]
  {
    unsigned short* dst = (by == 0) ? xl : (by == 1) ? xr : xs;
    const bool doG = (by != 1);
    float* eps = (float*)smem + w * 1088;          // 16x68 f32 private (<= 34816B)
    float* gpart = (float*)(smem + 40960);         // [256][4] f32 = 4KB
    float biasn[4], wcn[4];
#pragma unroll
    for (int n = 0; n < 4; ++n) {
      biasn[n] = bcat[colBase + wn + n * 16 + (lane & 15)];
      wcn[n] = Wcls[wn + n * 16 + (lane & 15)];
    }
#pragma unroll
    for (int m = 0; m < 8; ++m) {
      float rp[4] = {0.f, 0.f, 0.f, 0.f};
#pragma unroll
      for (int n = 0; n < 4; ++n)
#pragma unroll
        for (int j = 0; j < 4; ++j) {
          const float v = acc[m][n][j] + biasn[n];
          eps[((lane >> 4) * 4 + j) * 68 + n * 16 + (lane & 15)] = v;
          rp[j] += v * wcn[n];
        }
#pragma unroll
      for (int it = 0; it < 2; ++it) {
        const int r16 = it * 8 + (lane >> 3);
        const int c8 = (lane & 7) * 8;
        const float* srcp = eps + r16 * 68 + c8;
        float4 v0 = *(const float4*)srcp;
        float4 v1 = *(const float4*)(srcp + 4);
        uint4 o;
        o.x = pk2(v0.x, v0.y);
        o.y = pk2(v0.z, v0.w);
        o.z = pk2(v1.x, v1.y);
        o.w = pk2(v1.z, v1.w);
        *(uint4*)(dst + (size_t)(rowBase + wm + m * 16 + r16) * 256 + wn + c8) = o;
      }
      if (doG) {
#pragma unroll
        for (int j = 0; j < 4; ++j) {
          float s = rp[j];
          s += __shfl_xor(s, 1);
          s += __shfl_xor(s, 2);
          s += __shfl_xor(s, 4);
          s += __shfl_xor(s, 8);
          if ((lane & 15) == 0)
            gpart[(wm + m * 16 + (lane >> 4) * 4 + j) * 4 + (w & 3)] = s;
        }
      }
    }
    __syncthreads();
    if (doG && tid < 256) {
      float s = gpart[tid * 4] + gpart[tid * 4 + 1] + gpart[tid * 4 + 2] + gpart[tid * 4 + 3];
      ((by == 0) ? g : gs)[rowBase + tid] = s;
    }
  }
}

// ---------------- per-edge attention logits (half-wave per edge) + direct slot scatter ----------------
__global__ __launch_bounds__(256) void edge_logit_kernel(
    const int* __restrict__ ei,          // [2][NEDGE]
    const unsigned short* __restrict__ xl,
    const unsigned short* __restrict__ xr,
    const float* __restrict__ att,
    int* __restrict__ cnt,
    int* __restrict__ slot_src,          // [NNODE][SLOTCAP]
    float* __restrict__ slot_e) {        // [NNODE][SLOTCAP]
  const int j = blockIdx.x * 8 + (threadIdx.x >> 5);
  const int lane = threadIdx.x & 31;
  int src, dst;
  if (j < NEDGE) { src = ei[j]; dst = ei[NEDGE + j]; }
  else           { src = j - NEDGE; dst = src; }
  const int c = lane * 8;
  uint4 ul = *(const uint4*)(xl + (size_t)src * 256 + c);
  uint4 ur = *(const uint4*)(xr + (size_t)dst * 256 + c);
  float4 a0 = *(const float4*)(att + c);
  float4 a1 = *(const float4*)(att + c + 4);
  float s = lrelu(b2f((unsigned short)ul.x) + b2f((unsigned short)ur.x)) * a0.x
          + lrelu(b2f((unsigned short)(ul.x >> 16)) + b2f((unsigned short)(ur.x >> 16))) * a0.y
          + lrelu(b2f((unsigned short)ul.y) + b2f((unsigned short)ur.y)) * a0.z
          + lrelu(b2f((unsigned short)(ul.y >> 16)) + b2f((unsigned short)(ur.y >> 16))) * a0.w
          + lrelu(b2f((unsigned short)ul.z) + b2f((unsigned short)ur.z)) * a1.x
          + lrelu(b2f((unsigned short)(ul.z >> 16)) + b2f((unsigned short)(ur.z >> 16))) * a1.y
          + lrelu(b2f((unsigned short)ul.w) + b2f((unsigned short)ur.w)) * a1.z
          + lrelu(b2f((unsigned short)(ul.w >> 16)) + b2f((unsigned short)(ur.w >> 16))) * a1.w;
#pragma unroll
  for (int off = 16; off; off >>= 1) s += __shfl_xor(s, off);
  if (lane == 0) {
    const int pos = atomicAdd(&cnt[dst], 1);
    if (pos < SLOTCAP) {
      slot_src[dst * SLOTCAP + pos] = src;
      slot_e[dst * SLOTCAP + pos] = s;
    }
  }
}

// ---------------- per-node cls logit from g/gs (softmax shift-invariance drops the const) ------
__global__ __launch_bounds__(256) void logit_kernel(
    const int* __restrict__ cnt,
    const int* __restrict__ slot_src, const float* __restrict__ slot_e,
    const float* __restrict__ g, const float* __restrict__ gs,
    float* __restrict__ logits) {
  const int n = blockIdx.x * 256 + threadIdx.x;
  const int base = n * SLOTCAP;
  const int deg = cnt[n];
  float m = -1e30f;
  for (int k = 0; k < deg; ++k) m = fmaxf(m, slot_e[base + k]);
  float denom = 0.f, wsum = 0.f;
  for (int k = 0; k < deg; ++k) {
    const float p = __expf(slot_e[base + k] - m);
    denom += p;
    wsum += p * g[slot_src[base + k]];
  }
  logits[n] = gs[n] + wsum / denom;
}

// ---------------- per-node softmax + aggregate + fused sinkhorn add (wave per node) ----------------
__global__ __launch_bounds__(256) void node_sk_kernel(
    const int* __restrict__ cnt,
    const int* __restrict__ slot_src, const float* __restrict__ slot_e,
    const unsigned short* __restrict__ xl,
    const unsigned short* __restrict__ xs,
    const float* __restrict__ conv_bias,
    const float* __restrict__ logits,
    float* __restrict__ out) {
  const int n = blockIdx.x * 4 + (threadIdx.x >> 6);
  const int lane = threadIdx.x & 63;
  const int base = n * SLOTCAP;
  const int deg = cnt[n];

  float m = -1e30f;
  for (int k = 0; k < deg; ++k) m = fmaxf(m, slot_e[base + k]);
  float denom = 0.f;
  for (int k = 0; k < deg; ++k) denom += __expf(slot_e[base + k] - m);
  const float inv = 1.f / denom;

  const int c = lane * 4;
  float4 accv = {0.f, 0.f, 0.f, 0.f};
  for (int k = 0; k < deg; ++k) {
    const float alpha = __expf(slot_e[base + k] - m) * inv;
    const int src = slot_src[base + k];
    ushort4 u = *(const ushort4*)(xl + (size_t)src * 256 + c);
    accv.x += alpha * b2f(u.x);
    accv.y += alpha * b2f(u.y);
    accv.z += alpha * b2f(u.z);
    accv.w += alpha * b2f(u.w);
  }

  // row softmax of logits (sinkhorn channel): wave holds all 256 row logits (4/lane)
  const int r = n >> 8;
  float4 lv = *(const float4*)(logits + r * 256 + c);
  float lm = fmaxf(fmaxf(lv.x, lv.y), fmaxf(lv.z, lv.w));
#pragma unroll
  for (int off = 32; off; off >>= 1) lm = fmaxf(lm, __shfl_xor(lm, off));
  float ls = __expf(lv.x - lm) + __expf(lv.y - lm) + __expf(lv.z - lm) + __expf(lv.w - lm);
#pragma unroll
  for (int off = 32; off; off >>= 1) ls += __shfl_xor(ls, off);
  const float softval = __expf(logits[n] - lm) / ls;

  ushort4 s4 = *(const ushort4*)(xs + (size_t)n * 256 + c);
  float4 cb = *(const float4*)(conv_bias + c);
  float4 cur;
  cur.x = b2f(s4.x) + accv.x + cb.x + softval;
  cur.y = b2f(s4.y) + accv.y + cb.y + softval;
  cur.z = b2f(s4.z) + accv.z + cb.z + softval;
  cur.w = b2f(s4.w) + accv.w + cb.w + softval;
  *(float4*)(out + (size_t)n * 256 + c) = cur;
}

// ---------------- launch ----------------
extern "C" void kernel_launch(void* const* d_in, const int* in_sizes, int n_in,
                              void* d_out, int out_size, void* d_ws, size_t ws_size,
                              hipStream_t stream) {
  const float* x        = (const float*)d_in[0];
  const int*   ei       = (const int*)d_in[2];
  const float* W_self   = (const float*)d_in[5];
  const float* b_self   = (const float*)d_in[6];
  const float* W_l      = (const float*)d_in[7];
  const float* b_l      = (const float*)d_in[8];
  const float* W_r      = (const float*)d_in[9];
  const float* b_r      = (const float*)d_in[10];
  const float* att      = (const float*)d_in[11];
  const float* conv_bias= (const float*)d_in[12];
  const float* W_cls    = (const float*)d_in[13];
  float* out = (float*)d_out;

  char* ws = (char*)d_ws;
  size_t off = 0;
  auto alloc = [&](size_t bytes) {
    char* p = ws + off;
    off += (bytes + 255) & ~(size_t)255;
    return p;
  };
  unsigned short* xb   = (unsigned short*)alloc((size_t)NNODE * INC * 2);  // dead after gemm
  unsigned short* WT   = (unsigned short*)alloc((size_t)768 * 512 * 2);
  float*          bcat = (float*)alloc(768 * 4);
  unsigned short* xlb  = (unsigned short*)alloc((size_t)NNODE * OUTC * 2);
  unsigned short* xrb  = (unsigned short*)alloc((size_t)NNODE * OUTC * 2);
  unsigned short* xsb  = (unsigned short*)alloc((size_t)NNODE * OUTC * 2);
  int*            cnt  = (int*)alloc((size_t)NNODE * 4);
  float*          logits  = (float*)alloc((size_t)NNODE * 4);
  float*          gbuf    = (float*)alloc((size_t)NNODE * 4);
  float*          gsbuf   = (float*)alloc((size_t)NNODE * 4);
  // slot arrays overlay xb (dead after gemm)
  int*   slot_src = (int*)xb;
  float* slot_e   = (float*)(xb + (size_t)NNODE * SLOTCAP * 2);
  (void)ws_size; (void)in_sizes; (void)n_in; (void)out_size;

  prep_kernel<<<(NNODE * INC) / (256 * 8), 256, 0, stream>>>(x, xb, cnt,
                                                             W_l, W_r, W_self, b_l, b_r, b_self,
                                                             WT, bcat);
  gemm_kernel<<<768, 512, 0, stream>>>(xb, WT, bcat, W_cls, xlb, xrb, xsb, gbuf, gsbuf);
  edge_logit_kernel<<<ETOT / 8, 256, 0, stream>>>(ei, xlb, xrb, att, cnt, slot_src, slot_e);
  logit_kernel<<<NNODE / 256, 256, 0, stream>>>(cnt, slot_src, slot_e, gbuf, gsbuf, logits);
  node_sk_kernel<<<NNODE / 4, 256, 0, stream>>>(cnt, slot_src, slot_e, xlb, xsb, conv_bias,
                                                logits, out);
}